// Round 1
// baseline (53.324 us; speedup 1.0000x reference)
//
#include <hip/hip_runtime.h>
#include <math.h>

#define CHUNK 4096
#define K1_BLOCK 256
#define EPT 16          // elements per thread in K1 kernels (256*16 = 4096)
#define SEG_CAP 2048    // LDS segment cache in k_out

struct SegRec { float p0; int type; };  // type: 0=pre-note silence, 1=gated note, 2=release

__device__ __forceinline__ int wave_scan_i(int v) {
#pragma unroll
    for (int d = 1; d < 64; d <<= 1) {
        int n = __shfl_up(v, d, 64);
        if ((threadIdx.x & 63) >= d) v += n;
    }
    return v;
}
__device__ __forceinline__ float wave_scan_f(float v) {
#pragma unroll
    for (int d = 1; d < 64; d <<= 1) {
        float n = __shfl_up(v, d, 64);
        if ((threadIdx.x & 63) >= d) v += n;
    }
    return v;
}

// ---------------- K1a: per-chunk transition counts ----------------
__global__ void k_count(const float* __restrict__ g, int T, int* __restrict__ counts) {
    const int tid = threadIdx.x;
    const long base = (long)blockIdx.x * CHUNK + (long)tid * EPT;
    int c = 0;
    if (base < T) {
        const int n = (int)(((long)T - base) < EPT ? ((long)T - base) : (long)EPT);
        float prev = (base > 0) ? g[base - 1] : 0.0f;
        if (n == EPT) {
#pragma unroll
            for (int q = 0; q < EPT / 4; ++q) {
                const float4 v = *reinterpret_cast<const float4*>(g + base + q * 4);
                const long i0 = base + q * 4;
                if (i0 > 0) c += (v.x != prev);
                c += (v.y != v.x);
                c += (v.z != v.y);
                c += (v.w != v.z);
                prev = v.w;
            }
        } else {
            for (int e = 0; e < n; ++e) {
                const long i = base + e;
                const float cur = g[i];
                if (i > 0) c += (cur != prev);
                prev = cur;
            }
        }
    }
    __shared__ int lds[K1_BLOCK / 64];
    int s = wave_scan_i(c);
    if ((tid & 63) == 63) lds[tid >> 6] = s;
    __syncthreads();
    if (tid == 0) {
        int tot = 0;
        for (int w = 0; w < K1_BLOCK / 64; ++w) tot += lds[w];
        counts[blockIdx.x] = tot;
    }
}

// ---------------- K1b: exclusive scan of chunk counts ----------------
__global__ void __launch_bounds__(1024) k_scan(const int* __restrict__ counts,
                                               int* __restrict__ offsets, int n,
                                               int* __restrict__ ntrans) {
    __shared__ int lds[16];
    const int tid = threadIdx.x;
    const int lane = tid & 63, w = tid >> 6;
    int carry = 0;
    for (int basei = 0; basei < n; basei += 1024) {
        int idx = basei + tid;
        int v = (idx < n) ? counts[idx] : 0;
        int s = wave_scan_i(v);
        if (lane == 63) lds[w] = s;
        __syncthreads();
        if (w == 0) {
            int t = (lane < 16) ? lds[lane] : 0;
#pragma unroll
            for (int d = 1; d < 16; d <<= 1) {
                int nn = __shfl_up(t, d, 64);
                if (lane >= d) t += nn;
            }
            if (lane < 16) lds[lane] = t;
        }
        __syncthreads();
        int add = (w == 0) ? 0 : lds[w - 1];
        int incl = s + add;
        if (idx < n) offsets[idx] = carry + incl - v;
        int tile_total = lds[15];
        __syncthreads();
        carry += tile_total;
    }
    if (tid == 0) *ntrans = carry;
}

// ---------------- K1c: ordered transition index write ----------------
__global__ void k_write(const float* __restrict__ g, int T, const int* __restrict__ offsets,
                        int* __restrict__ trans, int captrans) {
    const int tid = threadIdx.x;
    const long base = (long)blockIdx.x * CHUNK + (long)tid * EPT;
    float vals[EPT];
    float prevFirst = 0.0f;
    int n = 0;
    if (base < T) {
        n = (int)(((long)T - base) < EPT ? ((long)T - base) : (long)EPT);
        prevFirst = (base > 0) ? g[base - 1] : 0.0f;
        if (n == EPT) {
#pragma unroll
            for (int q = 0; q < EPT / 4; ++q) {
                float4 v = *reinterpret_cast<const float4*>(g + base + q * 4);
                vals[q * 4 + 0] = v.x; vals[q * 4 + 1] = v.y;
                vals[q * 4 + 2] = v.z; vals[q * 4 + 3] = v.w;
            }
        } else {
            for (int e = 0; e < n; ++e) vals[e] = g[base + e];
        }
    }
    int c = 0;
    {
        float prev = prevFirst;
        for (int e = 0; e < n; ++e) {
            long i = base + e;
            if (i > 0) c += (vals[e] != prev);
            prev = vals[e];
        }
    }
    __shared__ int lds[K1_BLOCK / 64];
    const int lane = tid & 63, w = tid >> 6;
    int s = wave_scan_i(c);
    if (lane == 63) lds[w] = s;
    __syncthreads();
    if (w == 0) {
        int t = (lane < K1_BLOCK / 64) ? lds[lane] : 0;
#pragma unroll
        for (int d = 1; d < K1_BLOCK / 64; d <<= 1) {
            int nn = __shfl_up(t, d, 64);
            if (lane >= d) t += nn;
        }
        if (lane < K1_BLOCK / 64) lds[lane] = t;
    }
    __syncthreads();
    int add = (w == 0) ? 0 : lds[w - 1];
    int pos = offsets[blockIdx.x] + (s + add - c);
    {
        float prev = prevFirst;
        for (int e = 0; e < n; ++e) {
            long i = base + e;
            if (i > 0 && vals[e] != prev) {
                if (pos < captrans) trans[pos] = (int)i;
                ++pos;
            }
            prev = vals[e];
        }
    }
}

// ---------------- K2: per-segment records + prefix sum of retrigger seeds ----------------
__global__ void __launch_bounds__(1024) k_segs(
    const float* __restrict__ g, int T,
    const int* __restrict__ trans, const int* __restrict__ ntrans_p, int captrans,
    int* __restrict__ seg_starts, SegRec* __restrict__ recs, int* __restrict__ nseg_p,
    const float* __restrict__ attack_p, const float* __restrict__ decay_p,
    const float* __restrict__ sustain_p, const float* __restrict__ release_p) {
    const int tid = threadIdx.x;
    const int lane = tid & 63, w = tid >> 6;
    const float attack = *attack_p, decay = *decay_p;
    const float sustain = *sustain_p, release = *release_p;
    const float dtc = expf(-1.0f / decay);
    const float rtc = expf(-1.0f / release);
    const float dlog2 = log2f(dtc);
    const float rlog2 = log2f(rtc);
    const bool g0 = (g[0] != 0.0f);
    int ntrans = *ntrans_p;
    if (ntrans > captrans) ntrans = captrans;
    const int nseg = ntrans + 1;
    if (tid == 0) *nseg_p = nseg;

    __shared__ float lds[16];
    float carry = 0.0f;
    for (int basej = 0; basej < nseg; basej += 1024) {
        int j = basej + tid;
        bool valid = (j < nseg);
        int start = 0;
        bool gated = false;
        float r = 0.0f;
        if (valid) {
            start = (j == 0) ? 0 : trans[j - 1];
            gated = ((j & 1) == 0) ? g0 : !g0;
            if (gated && j >= 2) {
                // previous note = segment j-2; release between = segment j-1
                int startm1 = trans[j - 2];
                int startm2 = (j == 2) ? 0 : trans[j - 3];
                float lenprev = (float)(startm1 - startm2);   // prev note length = ad at note-off
                float seedp = (lenprev > attack)
                                  ? (sustain + (1.0f - sustain) * exp2f((lenprev - attack) * dlog2))
                                  : 1.0f;                      // off-during-attack -> seed 1
                float gap = (float)(start - startm1);          // release run length
                if (1.0f <= attack) r = seedp * exp2f(gap * rlog2);  // attack_mask at retrigger
            }
        }
        // block-wide inclusive scan of r (segment order)
        float s = wave_scan_f(r);
        if (lane == 63) lds[w] = s;
        __syncthreads();
        if (w == 0) {
            float t = (lane < 16) ? lds[lane] : 0.0f;
#pragma unroll
            for (int d = 1; d < 16; d <<= 1) {
                float nn = __shfl_up(t, d, 64);
                if (lane >= d) t += nn;
            }
            if (lane < 16) lds[lane] = t;
        }
        __syncthreads();
        float add = (w == 0) ? 0.0f : lds[w - 1];
        float incl = s + add;
        float tile_total = lds[15];
        if (valid) {
            seg_starts[j] = start;
            SegRec rec;
            if (gated) {
                rec.type = 1;
                rec.p0 = carry + incl;  // A: inclusive retrigger-seed sum
            } else if (j == 0) {
                rec.type = 0;  // silence before first note
                rec.p0 = 0.0f;
            } else {
                // release: seed from note j-1
                int sp = (j == 1) ? 0 : trans[j - 2];
                float len = (float)(start - sp);
                rec.type = 2;
                rec.p0 = (len > attack)
                             ? (sustain + (1.0f - sustain) * exp2f((len - attack) * dlog2))
                             : 1.0f;
            }
            recs[j] = rec;
        }
        __syncthreads();
        carry += tile_total;
    }
}

// ---------------- K3: per-sample evaluation ----------------
__global__ void k_out(float* __restrict__ out, int T,
                      const int* __restrict__ seg_starts, const SegRec* __restrict__ recs,
                      const int* __restrict__ nseg_p,
                      const float* __restrict__ attack_p, const float* __restrict__ decay_p,
                      const float* __restrict__ sustain_p, const float* __restrict__ release_p) {
    __shared__ int s_start[SEG_CAP];
    __shared__ float s_p0[SEG_CAP];
    __shared__ int s_type[SEG_CAP];
    const int nseg = *nseg_p;
    const bool useLds = (nseg <= SEG_CAP);
    if (useLds) {
        for (int j = threadIdx.x; j < nseg; j += blockDim.x) {
            s_start[j] = seg_starts[j];
            SegRec r = recs[j];
            s_p0[j] = r.p0;
            s_type[j] = r.type;
        }
        __syncthreads();
    }
    const float attack = *attack_p, decay = *decay_p;
    const float sustain = *sustain_p, release = *release_p;
    const float dlog2 = log2f(expf(-1.0f / decay));
    const float rlog2 = log2f(expf(-1.0f / release));
    const float inv_attack = 1.0f / attack;

    const long i0 = ((long)blockIdx.x * blockDim.x + threadIdx.x) * 4;
    if (i0 >= T) return;

    int lo = 0, hi = nseg - 1;
    if (useLds) {
        while (lo < hi) { int mid = (lo + hi + 1) >> 1; if (s_start[mid] <= i0) lo = mid; else hi = mid - 1; }
    } else {
        while (lo < hi) { int mid = (lo + hi + 1) >> 1; if (seg_starts[mid] <= i0) lo = mid; else hi = mid - 1; }
    }
    int j = lo;
    float res[4];
#pragma unroll
    for (int e = 0; e < 4; ++e) {
        const long i = i0 + e;
        if (i < T) {
            if (useLds) { while (j + 1 < nseg && s_start[j + 1] <= i) ++j; }
            else        { while (j + 1 < nseg && seg_starts[j + 1] <= i) ++j; }
            const int   type = useLds ? s_type[j] : recs[j].type;
            const float p0   = useLds ? s_p0[j]   : recs[j].p0;
            const int   st   = useLds ? s_start[j] : seg_starts[j];
            float v;
            if (type == 1) {
                const float ad = (float)(i - st + 1);  // samples since note-on (1-indexed)
                if (ad <= attack) v = (1.0f - p0) * ad * inv_attack + p0;
                else              v = sustain + (1.0f - sustain) * exp2f((ad - attack) * dlog2);
            } else if (type == 2) {
                const float k = (float)(i - st + 1);   // samples since note-off (1-indexed)
                v = p0 * exp2f(k * rlog2);
            } else {
                v = 0.0f;
            }
            res[e] = v;
        } else {
            res[e] = 0.0f;
        }
    }
    if (i0 + 3 < T) {
        *reinterpret_cast<float4*>(out + i0) = make_float4(res[0], res[1], res[2], res[3]);
    } else {
        for (int e = 0; e < 4; ++e)
            if (i0 + e < T) out[i0 + e] = res[e];
    }
}

extern "C" void kernel_launch(void* const* d_in, const int* in_sizes, int n_in,
                              void* d_out, int out_size, void* d_ws, size_t ws_size,
                              hipStream_t stream) {
    const float* gate    = (const float*)d_in[0];
    const float* attack  = (const float*)d_in[1];
    const float* decay   = (const float*)d_in[2];
    const float* sustain = (const float*)d_in[3];
    const float* release = (const float*)d_in[4];
    float* out = (float*)d_out;
    const int T = in_sizes[0];
    const int nchunk = (T + CHUNK - 1) / CHUNK;

    // workspace layout
    char* w = (char*)d_ws;
    int* ntrans_p = (int*)w;         // [0]
    int* nseg_p   = (int*)(w + 8);   // [8]
    int* counts   = (int*)(w + 256);
    int* offsets  = counts + nchunk;
    size_t head = 256 + (size_t)nchunk * 8;
    size_t remain = (ws_size > head + 128) ? (ws_size - head - 128) : 0;
    long captrans = (long)(remain / 16) - 2;  // 4B trans + 4B seg_start + 8B rec per transition
    if (captrans < 16) captrans = 16;
    if (captrans > (long)T) captrans = T;
    captrans &= ~1L;  // keep alignment
    int* trans      = offsets + nchunk;
    int* seg_starts = trans + captrans;
    SegRec* recs    = (SegRec*)(seg_starts + captrans + 2);

    k_count<<<nchunk, K1_BLOCK, 0, stream>>>(gate, T, counts);
    k_scan<<<1, 1024, 0, stream>>>(counts, offsets, nchunk, ntrans_p);
    k_write<<<nchunk, K1_BLOCK, 0, stream>>>(gate, T, offsets, trans, (int)captrans);
    k_segs<<<1, 1024, 0, stream>>>(gate, T, trans, ntrans_p, (int)captrans,
                                   seg_starts, recs, nseg_p,
                                   attack, decay, sustain, release);
    const int g3 = (int)((T + 1023) / 1024);
    k_out<<<g3, 256, 0, stream>>>(out, T, seg_starts, recs, nseg_p,
                                  attack, decay, sustain, release);
}